// Round 1
// baseline (735.664 us; speedup 1.0000x reference)
//
#include <hip/hip_runtime.h>
#include <stdint.h>

typedef __attribute__((ext_vector_type(8))) short vs8;   // 8 x bf16 (4 VGPR)
typedef __attribute__((ext_vector_type(4))) short vs4;
typedef __attribute__((ext_vector_type(4))) float vf4;   // MFMA accumulator

#define DEV static __device__ __forceinline__

DEV unsigned short f2bf(float x){
  union { float f; uint32_t u; } v; v.f = x;
  uint32_t r = v.u + 0x7fffu + ((v.u >> 16) & 1u);   // RNE to bf16
  return (unsigned short)(r >> 16);
}

DEV void gload_lds16(const void* g, void* l){
  __builtin_amdgcn_global_load_lds((const __attribute__((address_space(1))) void*)g,
                                   (__attribute__((address_space(3))) void*)l, 16, 0, 0);
}

// ---------------- weight convert fp32 -> bf16 ----------------
__global__ void cvt_w(const float* __restrict__ s, unsigned short* __restrict__ d, int n){
  int i = (blockIdx.x * blockDim.x + threadIdx.x) * 4;
  if (i >= n) return;
  vf4 f = *reinterpret_cast<const vf4*>(s + i);
  vs4 o;
  o[0] = (short)f2bf(f[0]); o[1] = (short)f2bf(f[1]);
  o[2] = (short)f2bf(f[2]); o[3] = (short)f2bf(f[3]);
  *reinterpret_cast<vs4*>(d + i) = o;
}

// ---------------- GEMM: C[M,N] = A[M,K] * B[N,K]^T (+bias) ----------------
// LDS tiles are [row][64] bf16 with 16B-slot XOR swizzle: phys_slot = slot ^ (row&7).

DEV void stage_f32(const float* __restrict__ g, long row0, int K, int kt,
                   unsigned short* lds, int tid){
  int r_ = tid >> 3, c = tid & 7;
#pragma unroll
  for (int i = 0; i < 4; ++i){
    int row = i*32 + r_;
    const float* src = g + (row0 + row) * (long)K + kt + c*8;
    vf4 f0 = *reinterpret_cast<const vf4*>(src);
    vf4 f1 = *reinterpret_cast<const vf4*>(src + 4);
    vs8 p;
    p[0]=(short)f2bf(f0[0]); p[1]=(short)f2bf(f0[1]); p[2]=(short)f2bf(f0[2]); p[3]=(short)f2bf(f0[3]);
    p[4]=(short)f2bf(f1[0]); p[5]=(short)f2bf(f1[1]); p[6]=(short)f2bf(f1[2]); p[7]=(short)f2bf(f1[3]);
    int slot = c ^ (row & 7);
    *reinterpret_cast<vs8*>(&lds[row*64 + slot*8]) = p;
  }
}

DEV void stage_bf16(const unsigned short* __restrict__ g, long row0, int K, int kt,
                    unsigned short* lds, int lane, int wid){
#pragma unroll
  for (int i = 0; i < 4; ++i){
    int stripe = wid*32 + i*8;                 // wave-uniform LDS base row
    int row = stripe + (lane >> 3);
    int chunk = (lane & 7) ^ (row & 7);        // pre-swizzle the global source
    const unsigned short* src = g + (row0 + row) * (long)K + kt + chunk*8;
    gload_lds16(src, &lds[stripe*64]);
  }
}

DEV vs8 lds_frag(const unsigned short* lds, int row, int slot){
  return *reinterpret_cast<const vs8*>(&lds[row*64 + (slot ^ (row & 7))*8]);
}

template<int A_F32, int B_F32, int OUT_F32, int BIAS_ROW>
__global__ __launch_bounds__(256)
void gemm_bt(const void* __restrict__ Ap, const void* __restrict__ Bp,
             const float* __restrict__ bias, void* __restrict__ Cp,
             int M, int N, int K, float oscale, long aB, long bB, long cB)
{
  __shared__ unsigned short As[128*64];
  __shared__ unsigned short Bs[128*64];
  const int tid = threadIdx.x, lane = tid & 63, wid = tid >> 6;
  const int nt = N >> 7, mt = M >> 7;
  int idx = blockIdx.x;
  const int per = mt * nt;
  const int batch = idx / per; idx -= batch * per;
  const long m0 = (long)(idx / nt) * 128;
  const long n0 = (long)(idx % nt) * 128;
  const int wm = (wid >> 1) * 64, wn = (wid & 1) * 64;
  const int cl = lane & 15, gr = lane >> 4;

  vf4 acc[4][4] = {};

  for (int kt = 0; kt < K; kt += 64){
    if (A_F32) stage_f32((const float*)Ap + aB*batch, m0, K, kt, As, tid);
    else       stage_bf16((const unsigned short*)Ap + aB*batch, m0, K, kt, As, lane, wid);
    if (B_F32) stage_f32((const float*)Bp + bB*batch, n0, K, kt, Bs, tid);
    else       stage_bf16((const unsigned short*)Bp + bB*batch, n0, K, kt, Bs, lane, wid);
    __syncthreads();
#pragma unroll
    for (int ks = 0; ks < 2; ++ks){
      vs8 af[4], bf[4];
#pragma unroll
      for (int mi = 0; mi < 4; ++mi) af[mi] = lds_frag(As, wm + mi*16 + cl, ks*4 + gr);
#pragma unroll
      for (int ni = 0; ni < 4; ++ni) bf[ni] = lds_frag(Bs, wn + ni*16 + cl, ks*4 + gr);
#pragma unroll
      for (int mi = 0; mi < 4; ++mi)
#pragma unroll
        for (int ni = 0; ni < 4; ++ni)
          acc[mi][ni] = __builtin_amdgcn_mfma_f32_16x16x32_bf16(af[mi], bf[ni], acc[mi][ni], 0, 0, 0);
    }
    __syncthreads();
  }

  // epilogue: D layout col = lane&15, row = (lane>>4)*4 + r  [guide m89]
#pragma unroll
  for (int mi = 0; mi < 4; ++mi)
#pragma unroll
    for (int ni = 0; ni < 4; ++ni)
#pragma unroll
      for (int r = 0; r < 4; ++r){
        long m = m0 + wm + mi*16 + gr*4 + r;
        long n = n0 + wn + ni*16 + cl;
        float v = (acc[mi][ni][r] + (BIAS_ROW ? bias[m] : bias[n])) * oscale;
        if (OUT_F32) (((float*)Cp) + cB*batch)[m*(long)N + n] = v;
        else (((unsigned short*)Cp) + cB*batch)[m*(long)N + n] = f2bf(v);
      }
}

// ---------------- flash attention ----------------
// q,k: [B,S,1024] bf16 (col = h*64+d); vT: [B, 1024(h*64+d), S] bf16
// q is pre-scaled by (1/sqrt(64))*log2(e) in its projection epilogue -> exp2 softmax.
__global__ __launch_bounds__(256)
void attn_kernel(const unsigned short* __restrict__ qg, const unsigned short* __restrict__ kg,
                 const unsigned short* __restrict__ vg, unsigned short* __restrict__ og)
{
  __shared__ unsigned short Pb[4][16*64];   // per-wave swizzled P tile
  const int tid = threadIdx.x, lane = tid & 63, wid = tid >> 6;
  int bid = blockIdx.x;
  const int qb = bid & 31;
  const int h  = (bid >> 5) & 15;
  const int b  = bid >> 9;
  const int s0 = qb*64 + wid*16;
  unsigned short* Pw = Pb[wid];
  const int cl = lane & 15, gr = lane >> 4;

  vs8 aq[2];
  {
    const unsigned short* qr = qg + ((long)(b*2048 + s0 + cl))*1024 + h*64 + gr*8;
    aq[0] = *reinterpret_cast<const vs8*>(qr);
    aq[1] = *reinterpret_cast<const vs8*>(qr + 32);
  }
  const unsigned short* kb = kg + ((long)b*2048)*1024 + h*64 + gr*8;
  const unsigned short* vb = vg + ((long)(b*1024 + h*64 + cl))*2048 + gr*8;

  vf4 cacc[4] = {};
  float mrow[4] = {-__builtin_inff(), -__builtin_inff(), -__builtin_inff(), -__builtin_inff()};
  float lrow[4] = {0.f, 0.f, 0.f, 0.f};

  for (int j0 = 0; j0 < 2048; j0 += 64){
    vf4 sc[4] = {};
#pragma unroll
    for (int jt = 0; jt < 4; ++jt){
      const unsigned short* kr = kb + (long)(j0 + jt*16 + cl)*1024;
      vs8 bk0 = *reinterpret_cast<const vs8*>(kr);
      vs8 bk1 = *reinterpret_cast<const vs8*>(kr + 32);
      sc[jt] = __builtin_amdgcn_mfma_f32_16x16x32_bf16(aq[0], bk0, sc[jt], 0, 0, 0);
      sc[jt] = __builtin_amdgcn_mfma_f32_16x16x32_bf16(aq[1], bk1, sc[jt], 0, 0, 0);
    }
    // online softmax (scores row i = gr*4+r, cols j = jt*16 + cl)
    float alpha[4];
#pragma unroll
    for (int r = 0; r < 4; ++r){
      float t = fmaxf(fmaxf(sc[0][r], sc[1][r]), fmaxf(sc[2][r], sc[3][r]));
      t = fmaxf(t, __shfl_xor(t, 1));
      t = fmaxf(t, __shfl_xor(t, 2));
      t = fmaxf(t, __shfl_xor(t, 4));
      t = fmaxf(t, __shfl_xor(t, 8));
      float mn = fmaxf(mrow[r], t);
      alpha[r] = exp2f(mrow[r] - mn);
      mrow[r] = mn;
    }
#pragma unroll
    for (int jt = 0; jt < 4; ++jt)
#pragma unroll
      for (int r = 0; r < 4; ++r)
        sc[jt][r] = exp2f(sc[jt][r] - mrow[r]);
#pragma unroll
    for (int r = 0; r < 4; ++r){
      float s = (sc[0][r] + sc[1][r]) + (sc[2][r] + sc[3][r]);
      s += __shfl_xor(s, 1);
      s += __shfl_xor(s, 2);
      s += __shfl_xor(s, 4);
      s += __shfl_xor(s, 8);
      lrow[r] = lrow[r]*alpha[r] + s;
    }
#pragma unroll
    for (int dt = 0; dt < 4; ++dt)
#pragma unroll
      for (int r = 0; r < 4; ++r)
        cacc[dt][r] *= alpha[r];
    // P (f32, D-layout) -> bf16 LDS [16][64], 16B-slot XOR swizzled
#pragma unroll
    for (int jt = 0; jt < 4; ++jt)
#pragma unroll
      for (int r = 0; r < 4; ++r){
        int i = gr*4 + r;
        int j = jt*16 + cl;
        Pw[i*64 + (((j >> 3) ^ (i & 7)) << 3) + (j & 7)] = f2bf(sc[jt][r]);
      }
    vs8 pa[2];
#pragma unroll
    for (int k2 = 0; k2 < 2; ++k2){
      int slot = k2*4 + gr;
      pa[k2] = *reinterpret_cast<const vs8*>(&Pw[cl*64 + (slot ^ (cl & 7))*8]);
    }
#pragma unroll
    for (int dt = 0; dt < 4; ++dt){
      const unsigned short* vr = vb + (long)dt*16*2048 + j0;
      vs8 bv0 = *reinterpret_cast<const vs8*>(vr);
      vs8 bv1 = *reinterpret_cast<const vs8*>(vr + 32);
      cacc[dt] = __builtin_amdgcn_mfma_f32_16x16x32_bf16(pa[0], bv0, cacc[dt], 0, 0, 0);
      cacc[dt] = __builtin_amdgcn_mfma_f32_16x16x32_bf16(pa[1], bv1, cacc[dt], 0, 0, 0);
    }
  }

  unsigned short* orow = og + ((long)(b*2048 + s0))*1024 + h*64 + cl;
#pragma unroll
  for (int r = 0; r < 4; ++r){
    float inv = 1.0f / lrow[r];
#pragma unroll
    for (int dt = 0; dt < 4; ++dt){
      int i = gr*4 + r;
      orow[(long)i*1024 + dt*16] = f2bf(cacc[dt][r] * inv);
    }
  }
}

// ---------------- launcher ----------------
extern "C" void kernel_launch(void* const* d_in, const int* in_sizes, int n_in,
                              void* d_out, int out_size, void* d_ws, size_t ws_size,
                              hipStream_t stream)
{
  (void)in_sizes; (void)n_in; (void)out_size; (void)ws_size;
  const float* Q  = (const float*)d_in[0];
  const float* K  = (const float*)d_in[1];
  const float* V  = (const float*)d_in[2];
  const float* bq = (const float*)d_in[4];
  const float* bk = (const float*)d_in[6];
  const float* bv = (const float*)d_in[8];
  const float* bo = (const float*)d_in[10];
  const float* Wq = (const float*)d_in[3];
  const float* Wk = (const float*)d_in[5];
  const float* Wv = (const float*)d_in[7];
  const float* Wo = (const float*)d_in[9];

  unsigned short* q   = (unsigned short*)d_ws;                 // [4,2048,1024] bf16
  unsigned short* k   = q   + (size_t)8*1024*1024;             // [4,2048,1024]
  unsigned short* vT  = k   + (size_t)8*1024*1024;             // [4,1024,2048]
  unsigned short* ctx = vT  + (size_t)8*1024*1024;             // [4,2048,1024]
  unsigned short* wqb = ctx + (size_t)8*1024*1024;             // [1024,1024]
  unsigned short* wkb = wqb + (size_t)1024*1024;
  unsigned short* wvb = wkb + (size_t)1024*1024;
  unsigned short* wob = wvb + (size_t)1024*1024;

  const int WN = 1024*1024;
  cvt_w<<<1024, 256, 0, stream>>>(Wq, wqb, WN);
  cvt_w<<<1024, 256, 0, stream>>>(Wk, wkb, WN);
  cvt_w<<<1024, 256, 0, stream>>>(Wv, wvb, WN);
  cvt_w<<<1024, 256, 0, stream>>>(Wo, wob, WN);

  const float qscale = 0.125f * 1.4426950408889634f;  // 1/sqrt(DK) * log2(e)

  // q = (Q @ Wq^T + bq) * qscale    [8192,1024]
  gemm_bt<1,0,0,0><<<512, 256, 0, stream>>>(Q, wqb, bq, q, 8192, 1024, 1024, qscale, 0, 0, 0);
  // k = K @ Wk^T + bk               [8192,1024]
  gemm_bt<1,0,0,0><<<512, 256, 0, stream>>>(K, wkb, bk, k, 8192, 1024, 1024, 1.0f, 0, 0, 0);
  // vT[b] = Wv @ V_b^T + bv(row)    [1024,2048] per batch
  gemm_bt<0,1,0,1><<<512, 256, 0, stream>>>(wvb, V, bv, vT, 1024, 2048, 1024, 1.0f,
                                            0, (long)2048*1024, (long)1024*2048);
  // attention -> ctx [4,2048,1024]
  attn_kernel<<<2048, 256, 0, stream>>>(q, k, vT, ctx);
  // out = ctx @ Wo^T + bo  (fp32)
  gemm_bt<0,0,1,0><<<512, 256, 0, stream>>>(ctx, wob, bo, d_out, 8192, 1024, 1024, 1.0f, 0, 0, 0);
}

// Round 6
// 478.565 us; speedup vs baseline: 1.5372x; 1.5372x over previous
//
#include <hip/hip_runtime.h>
#include <stdint.h>

typedef __attribute__((ext_vector_type(8))) short vs8;   // 8 x bf16 (4 VGPR)
typedef __attribute__((ext_vector_type(4))) short vs4;
typedef __attribute__((ext_vector_type(4))) float vf4;   // MFMA accumulator 16x16

#define DEV static __device__ __forceinline__

DEV unsigned short f2bf(float x){
  union { float f; uint32_t u; } v; v.f = x;
  uint32_t r = v.u + 0x7fffu + ((v.u >> 16) & 1u);   // RNE to bf16
  return (unsigned short)(r >> 16);
}

DEV void gload_lds16(const void* g, void* l){
  __builtin_amdgcn_global_load_lds((const __attribute__((address_space(1))) void*)g,
                                   (__attribute__((address_space(3))) void*)l, 16, 0, 0);
}

// ---------------- weight convert fp32 -> bf16 ----------------
__global__ void cvt_w(const float* __restrict__ s, unsigned short* __restrict__ d, int n){
  int i = (blockIdx.x * blockDim.x + threadIdx.x) * 4;
  if (i >= n) return;
  vf4 f = *reinterpret_cast<const vf4*>(s + i);
  vs4 o;
  o[0] = (short)f2bf(f[0]); o[1] = (short)f2bf(f[1]);
  o[2] = (short)f2bf(f[2]); o[3] = (short)f2bf(f[3]);
  *reinterpret_cast<vs4*>(d + i) = o;
}

// ---------------- GEMM: C[M,N] = A[M,K] * B[N,K]^T (+bias) ----------------
// LDS tiles are [row][64] bf16 with 16B-slot XOR swizzle: phys_slot = slot ^ (row&7).

DEV void stage_f32(const float* __restrict__ g, long row0, int K, int kt,
                   unsigned short* lds, int tid){
  int r_ = tid >> 3, c = tid & 7;
#pragma unroll
  for (int i = 0; i < 4; ++i){
    int row = i*32 + r_;
    const float* src = g + (row0 + row) * (long)K + kt + c*8;
    vf4 f0 = *reinterpret_cast<const vf4*>(src);
    vf4 f1 = *reinterpret_cast<const vf4*>(src + 4);
    vs8 p;
    p[0]=(short)f2bf(f0[0]); p[1]=(short)f2bf(f0[1]); p[2]=(short)f2bf(f0[2]); p[3]=(short)f2bf(f0[3]);
    p[4]=(short)f2bf(f1[0]); p[5]=(short)f2bf(f1[1]); p[6]=(short)f2bf(f1[2]); p[7]=(short)f2bf(f1[3]);
    int slot = c ^ (row & 7);
    *reinterpret_cast<vs8*>(&lds[row*64 + slot*8]) = p;
  }
}

DEV void stage_bf16(const unsigned short* __restrict__ g, long row0, int K, int kt,
                    unsigned short* lds, int lane, int wid){
#pragma unroll
  for (int i = 0; i < 4; ++i){
    int stripe = wid*32 + i*8;                 // wave-uniform LDS base row
    int row = stripe + (lane >> 3);
    int chunk = (lane & 7) ^ (row & 7);        // pre-swizzle the global source
    const unsigned short* src = g + (row0 + row) * (long)K + kt + chunk*8;
    gload_lds16(src, &lds[stripe*64]);
  }
}

DEV vs8 lds_frag(const unsigned short* lds, int row, int slot){
  return *reinterpret_cast<const vs8*>(&lds[row*64 + (slot ^ (row & 7))*8]);
}

template<int A_F32, int B_F32, int OUT_F32, int BIAS_ROW>
__global__ __launch_bounds__(256)
void gemm_bt(const void* __restrict__ Ap, const void* __restrict__ Bp,
             const float* __restrict__ bias, void* __restrict__ Cp,
             int M, int N, int K, float oscale, long aB, long bB, long cB)
{
  __shared__ unsigned short As[128*64];
  __shared__ unsigned short Bs[128*64];
  const int tid = threadIdx.x, lane = tid & 63, wid = tid >> 6;
  const int nt = N >> 7, mt = M >> 7;
  int idx = blockIdx.x;
  const int per = mt * nt;
  const int batch = idx / per; idx -= batch * per;
  const long m0 = (long)(idx / nt) * 128;
  const long n0 = (long)(idx % nt) * 128;
  const int wm = (wid >> 1) * 64, wn = (wid & 1) * 64;
  const int cl = lane & 15, gr = lane >> 4;

  vf4 acc[4][4] = {};

  for (int kt = 0; kt < K; kt += 64){
    if (A_F32) stage_f32((const float*)Ap + aB*batch, m0, K, kt, As, tid);
    else       stage_bf16((const unsigned short*)Ap + aB*batch, m0, K, kt, As, lane, wid);
    if (B_F32) stage_f32((const float*)Bp + bB*batch, n0, K, kt, Bs, tid);
    else       stage_bf16((const unsigned short*)Bp + bB*batch, n0, K, kt, Bs, lane, wid);
    __syncthreads();
#pragma unroll
    for (int ks = 0; ks < 2; ++ks){
      vs8 af[4], bf[4];
#pragma unroll
      for (int mi = 0; mi < 4; ++mi) af[mi] = lds_frag(As, wm + mi*16 + cl, ks*4 + gr);
#pragma unroll
      for (int ni = 0; ni < 4; ++ni) bf[ni] = lds_frag(Bs, wn + ni*16 + cl, ks*4 + gr);
#pragma unroll
      for (int mi = 0; mi < 4; ++mi)
#pragma unroll
        for (int ni = 0; ni < 4; ++ni)
          acc[mi][ni] = __builtin_amdgcn_mfma_f32_16x16x32_bf16(af[mi], bf[ni], acc[mi][ni], 0, 0, 0);
    }
    __syncthreads();
  }

  // epilogue: D layout col = lane&15, row = (lane>>4)*4 + r  [guide m89]
#pragma unroll
  for (int mi = 0; mi < 4; ++mi)
#pragma unroll
    for (int ni = 0; ni < 4; ++ni)
#pragma unroll
      for (int r = 0; r < 4; ++r){
        long m = m0 + wm + mi*16 + gr*4 + r;
        long n = n0 + wn + ni*16 + cl;
        float v = (acc[mi][ni][r] + (BIAS_ROW ? bias[m] : bias[n])) * oscale;
        if (OUT_F32) (((float*)Cp) + cB*batch)[m*(long)N + n] = v;
        else (((unsigned short*)Cp) + cB*batch)[m*(long)N + n] = f2bf(v);
      }
}

// ---------------- flash attention (swapped QK^T, 16x16x32 verified fragments) ----
// q,k: [B,S,1024] bf16 (col = h*64+d), q pre-scaled by (1/8)*log2(e).
// vT:  [B, 1024(h*64+d), S] bf16.
// Block = 4 waves; wave owns 16 q-rows; block covers 64 q-rows of one (b,h).
// Per 32-kv tile (double-buffered LDS, shared by 4 waves):
//   S^T = mfma(K, Q): lane (cl,gr) holds S[kv=jt*16+gr*4+r][q=cl] -> near-lane-local softmax
//   P^T staged to per-wave padded LDS (plain stores), PV: O^T = mfma(V^T, P^T).
// All fragment layouts are the round-1-hardware-verified 16x16x32 mappings.
__global__ __launch_bounds__(256)
void attn_kernel(const unsigned short* __restrict__ qg, const unsigned short* __restrict__ kg,
                 const unsigned short* __restrict__ vg, unsigned short* __restrict__ og)
{
  __shared__ __align__(16) unsigned short Ks[2][32*64];    // [32 kv][8 slot ^ (kv&7)][8]
  __shared__ __align__(16) unsigned short Vs[2][4*64*8];   // [4 kv-slot][64 d][8]
  __shared__ __align__(16) unsigned short Pl[4][16*40];    // per-wave P^T: [16 q][32 kv + 8 pad]
  const int tid = threadIdx.x, lane = tid & 63, wid = tid >> 6;
  const int cl = lane & 15, gr = lane >> 4;
  const int bid = blockIdx.x;
  const int qb = bid & 31, h = (bid >> 5) & 15, b = bid >> 9;
  const int s0 = qb*64 + wid*16;

  // Q B-fragments (verified): col=cl=q, k=d = kc*32 + gr*8 + e
  const unsigned short* qp = qg + ((long)(b*2048 + s0 + cl))*1024 + h*64 + gr*8;
  vs8 q0 = *(const vs8*)(qp);
  vs8 q1 = *(const vs8*)(qp + 32);

  const unsigned short* kb = kg + ((long)b*2048)*1024 + h*64;
  const unsigned short* vb = vg + ((long)(b*1024) + h*64)*2048;

  vf4 o0 = {}, o1 = {}, o2 = {}, o3 = {};
  float m = -__builtin_inff(), lsum = 0.f;

  const int krow = tid >> 3, ksl = tid & 7;          // K staging coords (32 rows x 8 chunks)
  const int vd = tid >> 2, vsl = tid & 3;            // V staging coords (64 d x 4 kv-slots)
  unsigned short* ldsK0 = &Ks[0][(tid & 192)*8];     // wave-uniform bases
  unsigned short* ldsK1 = &Ks[1][(tid & 192)*8];
  unsigned short* Pw = Pl[wid];

  // prologue: stage tile 0
  gload_lds16(kb + (long)krow*1024 + ((ksl ^ (krow & 7))*8), ldsK0);
  {
    vs8 vr = *(const vs8*)(vb + (long)vd*2048 + vsl*8);
    *(vs8*)(&Vs[0][(vsl*64 + vd)*8]) = vr;
  }
  __syncthreads();

  int cur = 0;
  for (int j0 = 0; j0 < 2048; j0 += 32){
    const int more = (j0 + 32) < 2048;
    vs8 vr;
    if (more){
      gload_lds16(kb + (long)(j0 + 32 + krow)*1024 + ((ksl ^ (krow & 7))*8),
                  cur ? ldsK0 : ldsK1);
      vr = *(const vs8*)(vb + (long)vd*2048 + (j0 + 32) + vsl*8);
    }
    const unsigned short* ksb = Ks[cur];
    const unsigned short* vsb = Vs[cur];

    // S^T = K * Q^T: A = K rows (row=cl=kv within subtile), B = Q (col=cl=q)
    vf4 sa = {}, sb = {};
    {
      vs8 a00 = lds_frag(ksb, cl,      gr);       // kv 0..15, d 0..31
      vs8 a01 = lds_frag(ksb, cl,      4 + gr);   // kv 0..15, d 32..63
      sa = __builtin_amdgcn_mfma_f32_16x16x32_bf16(a00, q0, sa, 0, 0, 0);
      sa = __builtin_amdgcn_mfma_f32_16x16x32_bf16(a01, q1, sa, 0, 0, 0);
      vs8 a10 = lds_frag(ksb, 16 + cl, gr);       // kv 16..31
      vs8 a11 = lds_frag(ksb, 16 + cl, 4 + gr);
      sb = __builtin_amdgcn_mfma_f32_16x16x32_bf16(a10, q0, sb, 0, 0, 0);
      sb = __builtin_amdgcn_mfma_f32_16x16x32_bf16(a11, q1, sb, 0, 0, 0);
    }
    // lane (cl,gr) holds S[kv = jt*16 + gr*4 + r][q = cl]  (log2-domain, prescaled)
    float t = fmaxf(fmaxf(fmaxf(sa[0], sa[1]), fmaxf(sa[2], sa[3])),
                    fmaxf(fmaxf(sb[0], sb[1]), fmaxf(sb[2], sb[3])));
    t = fmaxf(t, __shfl_xor(t, 16));
    t = fmaxf(t, __shfl_xor(t, 32));   // all 4 gr-lanes of q=cl agree
    float mn = fmaxf(m, t);
    float al = exp2f(m - mn);
    m = mn;
    lsum *= al;
#pragma unroll
    for (int r = 0; r < 4; ++r){ o0[r] *= al; o1[r] *= al; o2[r] *= al; o3[r] *= al; }
#pragma unroll
    for (int r = 0; r < 4; ++r){ sa[r] = exp2f(sa[r] - m); sb[r] = exp2f(sb[r] - m); }
    lsum += ((sa[0]+sa[1]) + (sa[2]+sa[3])) + ((sb[0]+sb[1]) + (sb[2]+sb[3]));

    // P^T -> per-wave LDS rows (q=cl), cols kv; manual bf16 packing (verified f2bf)
    int2 wa, wb;
    wa.x = (int)(unsigned)f2bf(sa[0]) | ((int)(unsigned)f2bf(sa[1]) << 16);
    wa.y = (int)(unsigned)f2bf(sa[2]) | ((int)(unsigned)f2bf(sa[3]) << 16);
    wb.x = (int)(unsigned)f2bf(sb[0]) | ((int)(unsigned)f2bf(sb[1]) << 16);
    wb.y = (int)(unsigned)f2bf(sb[2]) | ((int)(unsigned)f2bf(sb[3]) << 16);
    *reinterpret_cast<int2*>(&Pw[cl*40 + gr*4])      = wa;   // kv gr*4..+3
    *reinterpret_cast<int2*>(&Pw[cl*40 + 16 + gr*4]) = wb;   // kv 16+gr*4..+3

    // B-frag of P^T: col=cl=q, k = kv = gr*8 + e  (wave-private; compiler orders lgkm)
    vs8 pa = *reinterpret_cast<const vs8*>(&Pw[cl*40 + gr*8]);

    // O^T += V^T * P^T: A = V^T (row=cl=d within d-tile, k = kv = gr*8+e)
    o0 = __builtin_amdgcn_mfma_f32_16x16x32_bf16(*(const vs8*)(vsb + (gr*64 +  0 + cl)*8), pa, o0, 0, 0, 0);
    o1 = __builtin_amdgcn_mfma_f32_16x16x32_bf16(*(const vs8*)(vsb + (gr*64 + 16 + cl)*8), pa, o1, 0, 0, 0);
    o2 = __builtin_amdgcn_mfma_f32_16x16x32_bf16(*(const vs8*)(vsb + (gr*64 + 32 + cl)*8), pa, o2, 0, 0, 0);
    o3 = __builtin_amdgcn_mfma_f32_16x16x32_bf16(*(const vs8*)(vsb + (gr*64 + 48 + cl)*8), pa, o3, 0, 0, 0);

    if (more) *(vs8*)(&Vs[cur ^ 1][(vsl*64 + vd)*8]) = vr;  // write-late (T14)
    __syncthreads();
    cur ^= 1;
  }

  // epilogue: combine l over gr, write O[q=cl][d = dt*16 + gr*4 + r]
  float ls = lsum;
  ls += __shfl_xor(ls, 16);
  ls += __shfl_xor(ls, 32);
  float inv = 1.0f / ls;
  unsigned short* ob = og + ((long)(b*2048 + s0 + cl))*1024 + h*64 + gr*4;
  vs4 w0, w1, w2, w3;
#pragma unroll
  for (int r = 0; r < 4; ++r){
    w0[r] = (short)f2bf(o0[r] * inv);
    w1[r] = (short)f2bf(o1[r] * inv);
    w2[r] = (short)f2bf(o2[r] * inv);
    w3[r] = (short)f2bf(o3[r] * inv);
  }
  *(vs4*)(ob +  0) = w0;
  *(vs4*)(ob + 16) = w1;
  *(vs4*)(ob + 32) = w2;
  *(vs4*)(ob + 48) = w3;
}

// ---------------- launcher ----------------
extern "C" void kernel_launch(void* const* d_in, const int* in_sizes, int n_in,
                              void* d_out, int out_size, void* d_ws, size_t ws_size,
                              hipStream_t stream)
{
  (void)in_sizes; (void)n_in; (void)out_size; (void)ws_size;
  const float* Q  = (const float*)d_in[0];
  const float* K  = (const float*)d_in[1];
  const float* V  = (const float*)d_in[2];
  const float* bq = (const float*)d_in[4];
  const float* bk = (const float*)d_in[6];
  const float* bv = (const float*)d_in[8];
  const float* bo = (const float*)d_in[10];
  const float* Wq = (const float*)d_in[3];
  const float* Wk = (const float*)d_in[5];
  const float* Wv = (const float*)d_in[7];
  const float* Wo = (const float*)d_in[9];

  unsigned short* q   = (unsigned short*)d_ws;                 // [4,2048,1024] bf16
  unsigned short* k   = q   + (size_t)8*1024*1024;             // [4,2048,1024]
  unsigned short* vT  = k   + (size_t)8*1024*1024;             // [4,1024,2048]
  unsigned short* ctx = vT  + (size_t)8*1024*1024;             // [4,2048,1024]
  unsigned short* wqb = ctx + (size_t)8*1024*1024;             // [1024,1024]
  unsigned short* wkb = wqb + (size_t)1024*1024;
  unsigned short* wvb = wkb + (size_t)1024*1024;
  unsigned short* wob = wvb + (size_t)1024*1024;

  const int WN = 1024*1024;
  cvt_w<<<1024, 256, 0, stream>>>(Wq, wqb, WN);
  cvt_w<<<1024, 256, 0, stream>>>(Wk, wkb, WN);
  cvt_w<<<1024, 256, 0, stream>>>(Wv, wvb, WN);
  cvt_w<<<1024, 256, 0, stream>>>(Wo, wob, WN);

  const float qscale = 0.125f * 1.4426950408889634f;  // 1/sqrt(DK) * log2(e)

  // q = (Q @ Wq^T + bq) * qscale    [8192,1024]
  gemm_bt<1,0,0,0><<<512, 256, 0, stream>>>(Q, wqb, bq, q, 8192, 1024, 1024, qscale, 0, 0, 0);
  // k = K @ Wk^T + bk               [8192,1024]
  gemm_bt<1,0,0,0><<<512, 256, 0, stream>>>(K, wkb, bk, k, 8192, 1024, 1024, 1.0f, 0, 0, 0);
  // vT[b] = Wv @ V_b^T + bv(row)    [1024,2048] per batch
  gemm_bt<0,1,0,1><<<512, 256, 0, stream>>>(wvb, V, bv, vT, 1024, 2048, 1024, 1.0f,
                                            0, (long)2048*1024, (long)1024*2048);
  // attention -> ctx [4,2048,1024]
  attn_kernel<<<2048, 256, 0, stream>>>(q, k, vT, ctx);
  // out = ctx @ Wo^T + bo  (fp32)
  gemm_bt<0,0,1,0><<<512, 256, 0, stream>>>(ctx, wob, bo, d_out, 8192, 1024, 1024, 1.0f, 0, 0, 0);
}

// Round 7
// 416.691 us; speedup vs baseline: 1.7655x; 1.1485x over previous
//
#include <hip/hip_runtime.h>
#include <stdint.h>

typedef __attribute__((ext_vector_type(8))) short vs8;   // 8 x bf16 (4 VGPR)
typedef __attribute__((ext_vector_type(4))) short vs4;
typedef __attribute__((ext_vector_type(4))) float vf4;   // MFMA accumulator 16x16

#define DEV static __device__ __forceinline__

DEV unsigned short f2bf(float x){
  union { float f; uint32_t u; } v; v.f = x;
  uint32_t r = v.u + 0x7fffu + ((v.u >> 16) & 1u);   // RNE to bf16
  return (unsigned short)(r >> 16);
}

DEV void gload_lds16(const void* g, void* l){
  __builtin_amdgcn_global_load_lds((const __attribute__((address_space(1))) void*)g,
                                   (__attribute__((address_space(3))) void*)l, 16, 0, 0);
}

DEV int cvtpk(float lo, float hi_){
  int r; asm("v_cvt_pk_bf16_f32 %0, %1, %2" : "=v"(r) : "v"(lo), "v"(hi_)); return r;
}

// ---------------- fp32 -> bf16 convert (weights and activations) ----------------
__global__ void cvt_w(const float* __restrict__ s, unsigned short* __restrict__ d, int n){
  int i = (blockIdx.x * blockDim.x + threadIdx.x) * 4;
  if (i >= n) return;
  vf4 f = *reinterpret_cast<const vf4*>(s + i);
  vs4 o;
  o[0] = (short)f2bf(f[0]); o[1] = (short)f2bf(f[1]);
  o[2] = (short)f2bf(f[2]); o[3] = (short)f2bf(f[3]);
  *reinterpret_cast<vs4*>(d + i) = o;
}

// ---------------- GEMM: C[M,N] = A[M,K] * B[N,K]^T (+bias) ----------------
// LDS tiles are [row][64] bf16 with 16B-slot XOR swizzle: phys_slot = slot ^ (row&7).

DEV void stage_bf16(const unsigned short* __restrict__ g, long row0, int K, int kt,
                    unsigned short* lds, int lane, int wid){
#pragma unroll
  for (int i = 0; i < 4; ++i){
    int stripe = wid*32 + i*8;                 // wave-uniform LDS base row
    int row = stripe + (lane >> 3);
    int chunk = (lane & 7) ^ (row & 7);        // pre-swizzle the global source
    const unsigned short* src = g + (row0 + row) * (long)K + kt + chunk*8;
    gload_lds16(src, &lds[stripe*64]);
  }
}

DEV vs8 lds_frag(const unsigned short* lds, int row, int slot){
  return *reinterpret_cast<const vs8*>(&lds[row*64 + (slot ^ (row & 7))*8]);
}

template<int OUT_F32, int BIAS_ROW>
__global__ __launch_bounds__(256)
void gemm_bt(const unsigned short* __restrict__ Ap, const unsigned short* __restrict__ Bp,
             const float* __restrict__ bias, void* __restrict__ Cp,
             int M, int N, int K, float oscale, long aB, long bB, long cB)
{
  __shared__ unsigned short As[128*64];
  __shared__ unsigned short Bs[128*64];
  const int tid = threadIdx.x, lane = tid & 63, wid = tid >> 6;
  const int nt = N >> 7, mt = M >> 7;
  int idx = blockIdx.x;
  const int per = mt * nt;
  const int batch = idx / per; idx -= batch * per;
  const long m0 = (long)(idx / nt) * 128;
  const long n0 = (long)(idx % nt) * 128;
  const int wm = (wid >> 1) * 64, wn = (wid & 1) * 64;
  const int cl = lane & 15, gr = lane >> 4;

  vf4 acc[4][4] = {};

  for (int kt = 0; kt < K; kt += 64){
    stage_bf16(Ap + aB*batch, m0, K, kt, As, lane, wid);
    stage_bf16(Bp + bB*batch, n0, K, kt, Bs, lane, wid);
    __syncthreads();
#pragma unroll
    for (int ks = 0; ks < 2; ++ks){
      vs8 af[4], bf[4];
#pragma unroll
      for (int mi = 0; mi < 4; ++mi) af[mi] = lds_frag(As, wm + mi*16 + cl, ks*4 + gr);
#pragma unroll
      for (int ni = 0; ni < 4; ++ni) bf[ni] = lds_frag(Bs, wn + ni*16 + cl, ks*4 + gr);
#pragma unroll
      for (int mi = 0; mi < 4; ++mi)
#pragma unroll
        for (int ni = 0; ni < 4; ++ni)
          acc[mi][ni] = __builtin_amdgcn_mfma_f32_16x16x32_bf16(af[mi], bf[ni], acc[mi][ni], 0, 0, 0);
    }
    __syncthreads();
  }

  // epilogue: D layout col = lane&15, row = (lane>>4)*4 + r  [guide m89]
#pragma unroll
  for (int mi = 0; mi < 4; ++mi)
#pragma unroll
    for (int ni = 0; ni < 4; ++ni)
#pragma unroll
      for (int r = 0; r < 4; ++r){
        long m = m0 + wm + mi*16 + gr*4 + r;
        long n = n0 + wn + ni*16 + cl;
        float v = (acc[mi][ni][r] + (BIAS_ROW ? bias[m] : bias[n])) * oscale;
        if (OUT_F32) (((float*)Cp) + cB*batch)[m*(long)N + n] = v;
        else (((unsigned short*)Cp) + cB*batch)[m*(long)N + n] = f2bf(v);
      }
}

// ---------------- flash attention (swapped QK^T, KVBLK=64, verified fragments) ----
// q,k: [B,S,1024] bf16 (col = h*64+d), q pre-scaled by (1/8)*log2(e).
// vT:  [B, 1024(h*64+d), S] bf16.
// Block = 4 waves; wave owns 16 q-rows; block covers 64 q-rows of one (b,h).
// Per 64-kv tile (double-buffered LDS, shared by 4 waves):
//   S^T = mfma(K, Q), in-register softmax (v_exp_f32, defer-max THR=8),
//   P^T via v_cvt_pk_bf16_f32 -> per-wave padded LDS, PV: O^T = mfma(V^T, P^T).
// Fragment layouts identical to the round-4/6-verified 16x16x32 mappings.
__global__ __launch_bounds__(256)
void attn_kernel(const unsigned short* __restrict__ qg, const unsigned short* __restrict__ kg,
                 const unsigned short* __restrict__ vg, unsigned short* __restrict__ og)
{
  __shared__ __align__(16) unsigned short Ks[2][64*64];    // [64 kv][8 slot ^ (kv&7)][8]
  __shared__ __align__(16) unsigned short Vs[2][8*64*8];   // [8 kv-slot][64 d][8]
  __shared__ __align__(16) unsigned short Pl[4][16*72];    // per-wave P^T: [16 q][64 kv + 8 pad]
  const int tid = threadIdx.x, lane = tid & 63, wid = tid >> 6;
  const int cl = lane & 15, gr = lane >> 4;
  const int bid = blockIdx.x;
  const int qb = bid & 31, h = (bid >> 5) & 15, b = bid >> 9;
  const int s0 = qb*64 + wid*16;

  // Q B-fragments (verified): col=cl=q, k=d = kc*32 + gr*8 + e
  const unsigned short* qp = qg + ((long)(b*2048 + s0 + cl))*1024 + h*64 + gr*8;
  vs8 q0 = *(const vs8*)(qp);
  vs8 q1 = *(const vs8*)(qp + 32);

  const unsigned short* kb = kg + ((long)b*2048)*1024 + h*64;
  const unsigned short* vb = vg + ((long)(b*1024) + h*64)*2048;

  vf4 o0 = {}, o1 = {}, o2 = {}, o3 = {};
  float m = -__builtin_inff(), lsum = 0.f;

  const int krow = tid >> 3;                          // 0..31 (+32 second pass)
  const int kchunk = ((tid & 7) ^ (krow & 7)) * 8;    // pre-swizzled source chunk
  const int vd = tid >> 2, vsl = tid & 3;             // V: d row, kv-slot (+4 second)
  const int kbase = (tid & 192) * 8;                  // wave-uniform LDS dest base
  unsigned short* Pw = Pl[wid];

  // prologue: stage tile 0
  gload_lds16(kb + (long)krow*1024 + kchunk,        &Ks[0][kbase]);
  gload_lds16(kb + (long)(krow + 32)*1024 + kchunk, &Ks[0][32*64 + kbase]);
  {
    vs8 va = *(const vs8*)(vb + (long)vd*2048 + vsl*8);
    vs8 vb2 = *(const vs8*)(vb + (long)vd*2048 + 32 + vsl*8);
    *(vs8*)(&Vs[0][(vsl*64 + vd)*8]) = va;
    *(vs8*)(&Vs[0][((vsl + 4)*64 + vd)*8]) = vb2;
  }
  __syncthreads();

  int cur = 0;
  for (int j0 = 0; j0 < 2048; j0 += 64){
    const int more = (j0 + 64) < 2048;
    vs8 va, vb2;
    if (more){
      const long nj = j0 + 64;
      gload_lds16(kb + (nj + krow)*1024 + kchunk,      &Ks[cur ^ 1][kbase]);
      gload_lds16(kb + (nj + krow + 32)*1024 + kchunk, &Ks[cur ^ 1][32*64 + kbase]);
      va  = *(const vs8*)(vb + (long)vd*2048 + nj + vsl*8);
      vb2 = *(const vs8*)(vb + (long)vd*2048 + nj + 32 + vsl*8);
    }
    const unsigned short* ksb = Ks[cur];
    const unsigned short* vsb = Vs[cur];

    // S^T = K * Q^T: 4 kv-subtiles of 16; lane holds S[kv=jt*16+gr*4+r][q=cl]
    vf4 s[4];
#pragma unroll
    for (int jt = 0; jt < 4; ++jt){
      vf4 z = {};
      vs8 aA = lds_frag(ksb, jt*16 + cl, gr);
      z = __builtin_amdgcn_mfma_f32_16x16x32_bf16(aA, q0, z, 0, 0, 0);
      vs8 aB = lds_frag(ksb, jt*16 + cl, 4 + gr);
      z = __builtin_amdgcn_mfma_f32_16x16x32_bf16(aB, q1, z, 0, 0, 0);
      s[jt] = z;
    }

    // tile max (16 own + cross-gr via 2 shfl), log2-domain prescaled
    float t0 = fmaxf(fmaxf(s[0][0], s[0][1]), fmaxf(s[0][2], s[0][3]));
    float t1 = fmaxf(fmaxf(s[1][0], s[1][1]), fmaxf(s[1][2], s[1][3]));
    float t2 = fmaxf(fmaxf(s[2][0], s[2][1]), fmaxf(s[2][2], s[2][3]));
    float t3 = fmaxf(fmaxf(s[3][0], s[3][1]), fmaxf(s[3][2], s[3][3]));
    float t = fmaxf(fmaxf(t0, t1), fmaxf(t2, t3));
    t = fmaxf(t, __shfl_xor(t, 16));
    t = fmaxf(t, __shfl_xor(t, 32));

    if (__any(t > m + 8.f)){            // defer-max (T13); first tile always taken
      float mn = fmaxf(m, t);
      float al = __builtin_amdgcn_exp2f(m - mn);
      m = mn; lsum *= al;
#pragma unroll
      for (int r = 0; r < 4; ++r){ o0[r] *= al; o1[r] *= al; o2[r] *= al; o3[r] *= al; }
    }

#pragma unroll
    for (int jt = 0; jt < 4; ++jt)
#pragma unroll
      for (int r = 0; r < 4; ++r)
        s[jt][r] = __builtin_amdgcn_exp2f(s[jt][r] - m);
    lsum += (((s[0][0]+s[0][1]) + (s[0][2]+s[0][3])) + ((s[1][0]+s[1][1]) + (s[1][2]+s[1][3])))
          + (((s[2][0]+s[2][1]) + (s[2][2]+s[2][3])) + ((s[3][0]+s[3][1]) + (s[3][2]+s[3][3])));

    // P^T -> per-wave LDS (row q=cl, col kv = jt*16+gr*4+r) via v_cvt_pk_bf16_f32
#pragma unroll
    for (int jt = 0; jt < 4; ++jt){
      int2 w;
      w.x = cvtpk(s[jt][0], s[jt][1]);
      w.y = cvtpk(s[jt][2], s[jt][3]);
      *reinterpret_cast<int2*>(&Pw[cl*72 + jt*16 + gr*4]) = w;
    }
    vs8 pa0 = *reinterpret_cast<const vs8*>(&Pw[cl*72 + gr*8]);        // kv 0..31 chunk
    vs8 pa1 = *reinterpret_cast<const vs8*>(&Pw[cl*72 + 32 + gr*8]);   // kv 32..63 chunk

    // O^T += V^T * P^T (A row = d within tile, k = kv)
    o0 = __builtin_amdgcn_mfma_f32_16x16x32_bf16(*(const vs8*)(vsb + (gr*64 +  0 + cl)*8), pa0, o0, 0, 0, 0);
    o1 = __builtin_amdgcn_mfma_f32_16x16x32_bf16(*(const vs8*)(vsb + (gr*64 + 16 + cl)*8), pa0, o1, 0, 0, 0);
    o2 = __builtin_amdgcn_mfma_f32_16x16x32_bf16(*(const vs8*)(vsb + (gr*64 + 32 + cl)*8), pa0, o2, 0, 0, 0);
    o3 = __builtin_amdgcn_mfma_f32_16x16x32_bf16(*(const vs8*)(vsb + (gr*64 + 48 + cl)*8), pa0, o3, 0, 0, 0);
    o0 = __builtin_amdgcn_mfma_f32_16x16x32_bf16(*(const vs8*)(vsb + ((4+gr)*64 +  0 + cl)*8), pa1, o0, 0, 0, 0);
    o1 = __builtin_amdgcn_mfma_f32_16x16x32_bf16(*(const vs8*)(vsb + ((4+gr)*64 + 16 + cl)*8), pa1, o1, 0, 0, 0);
    o2 = __builtin_amdgcn_mfma_f32_16x16x32_bf16(*(const vs8*)(vsb + ((4+gr)*64 + 32 + cl)*8), pa1, o2, 0, 0, 0);
    o3 = __builtin_amdgcn_mfma_f32_16x16x32_bf16(*(const vs8*)(vsb + ((4+gr)*64 + 48 + cl)*8), pa1, o3, 0, 0, 0);

    if (more){                               // write-late V staging (T14)
      *(vs8*)(&Vs[cur ^ 1][(vsl*64 + vd)*8]) = va;
      *(vs8*)(&Vs[cur ^ 1][((vsl + 4)*64 + vd)*8]) = vb2;
    }
    __syncthreads();
    cur ^= 1;
  }

  // epilogue: combine l over gr halves, write O[q=cl][d = dt*16 + gr*4 + r]
  float ls = lsum;
  ls += __shfl_xor(ls, 16);
  ls += __shfl_xor(ls, 32);
  float inv = 1.0f / ls;
  unsigned short* ob = og + ((long)(b*2048 + s0 + cl))*1024 + h*64 + gr*4;
  vs4 w0, w1, w2, w3;
#pragma unroll
  for (int r = 0; r < 4; ++r){
    w0[r] = (short)f2bf(o0[r] * inv);
    w1[r] = (short)f2bf(o1[r] * inv);
    w2[r] = (short)f2bf(o2[r] * inv);
    w3[r] = (short)f2bf(o3[r] * inv);
  }
  *(vs4*)(ob +  0) = w0;
  *(vs4*)(ob + 16) = w1;
  *(vs4*)(ob + 32) = w2;
  *(vs4*)(ob + 48) = w3;
}

// ---------------- launcher ----------------
extern "C" void kernel_launch(void* const* d_in, const int* in_sizes, int n_in,
                              void* d_out, int out_size, void* d_ws, size_t ws_size,
                              hipStream_t stream)
{
  (void)in_sizes; (void)n_in; (void)out_size; (void)ws_size;
  const float* Q  = (const float*)d_in[0];
  const float* K  = (const float*)d_in[1];
  const float* V  = (const float*)d_in[2];
  const float* bq = (const float*)d_in[4];
  const float* bk = (const float*)d_in[6];
  const float* bv = (const float*)d_in[8];
  const float* bo = (const float*)d_in[10];
  const float* Wq = (const float*)d_in[3];
  const float* Wk = (const float*)d_in[5];
  const float* Wv = (const float*)d_in[7];
  const float* Wo = (const float*)d_in[9];

  unsigned short* q   = (unsigned short*)d_ws;                 // [4,2048,1024] bf16
  unsigned short* k   = q   + (size_t)8*1024*1024;             // [4,2048,1024]
  unsigned short* vT  = k   + (size_t)8*1024*1024;             // [4,1024,2048]
  unsigned short* ctx = vT  + (size_t)8*1024*1024;             // [4,2048,1024]
  unsigned short* wqb = ctx + (size_t)8*1024*1024;             // [1024,1024]
  unsigned short* wkb = wqb + (size_t)1024*1024;
  unsigned short* wvb = wkb + (size_t)1024*1024;
  unsigned short* wob = wvb + (size_t)1024*1024;

  // bf16 input aliases (dead regions, stream-ordered):
  //   Qb -> ctx buffer (ctx not written until attn; q-proj consumes Qb first)
  //   Kb/Vb -> d_out halves (d_out only written by the final projection)
  unsigned short* Qb = ctx;
  unsigned short* Kb = (unsigned short*)d_out;
  unsigned short* Vb = Kb + (size_t)8*1024*1024;

  const int WN = 1024*1024;
  const int AN = 4*2048*1024;
  cvt_w<<<1024, 256, 0, stream>>>(Wq, wqb, WN);
  cvt_w<<<1024, 256, 0, stream>>>(Wk, wkb, WN);
  cvt_w<<<1024, 256, 0, stream>>>(Wv, wvb, WN);
  cvt_w<<<1024, 256, 0, stream>>>(Wo, wob, WN);
  cvt_w<<<8192, 256, 0, stream>>>(Q, Qb, AN);
  cvt_w<<<8192, 256, 0, stream>>>(K, Kb, AN);
  cvt_w<<<8192, 256, 0, stream>>>(V, Vb, AN);

  const float qscale = 0.125f * 1.4426950408889634f;  // 1/sqrt(DK) * log2(e)

  // q = (Q @ Wq^T + bq) * qscale    [8192,1024]
  gemm_bt<0,0><<<512, 256, 0, stream>>>(Qb, wqb, bq, q, 8192, 1024, 1024, qscale, 0, 0, 0);
  // k = K @ Wk^T + bk               [8192,1024]
  gemm_bt<0,0><<<512, 256, 0, stream>>>(Kb, wkb, bk, k, 8192, 1024, 1024, 1.0f, 0, 0, 0);
  // vT[b] = Wv @ V_b^T + bv(row)    [1024,2048] per batch
  gemm_bt<0,1><<<512, 256, 0, stream>>>(wvb, Vb, bv, vT, 1024, 2048, 1024, 1.0f,
                                        0, (long)2048*1024, (long)1024*2048);
  // attention -> ctx [4,2048,1024]  (overwrites Qb after q-proj is done)
  attn_kernel<<<2048, 256, 0, stream>>>(q, k, vT, ctx);
  // out = ctx @ Wo^T + bo  (fp32)   (overwrites Kb/Vb after they're consumed)
  gemm_bt<1,0><<<512, 256, 0, stream>>>(ctx, wob, bo, d_out, 8192, 1024, 1024, 1.0f, 0, 0, 0);
}

// Round 9
// 391.267 us; speedup vs baseline: 1.8802x; 1.0650x over previous
//
#include <hip/hip_runtime.h>
#include <stdint.h>

typedef __attribute__((ext_vector_type(8))) short vs8;   // 8 x bf16 (4 VGPR)
typedef __attribute__((ext_vector_type(4))) short vs4;
typedef __attribute__((ext_vector_type(4))) float vf4;   // MFMA accumulator 16x16

#define DEV static __device__ __forceinline__

DEV unsigned short f2bf(float x){
  union { float f; uint32_t u; } v; v.f = x;
  uint32_t r = v.u + 0x7fffu + ((v.u >> 16) & 1u);   // RNE to bf16
  return (unsigned short)(r >> 16);
}

DEV void gload_lds16(const void* g, void* l){
  __builtin_amdgcn_global_load_lds((const __attribute__((address_space(1))) void*)g,
                                   (__attribute__((address_space(3))) void*)l, 16, 0, 0);
}

DEV int cvtpk(float lo, float hi_){
  int r; asm("v_cvt_pk_bf16_f32 %0, %1, %2" : "=v"(r) : "v"(lo), "v"(hi_)); return r;
}

// ---------------- fp32 -> bf16 convert (weights and activations) ----------------
__global__ void cvt_w(const float* __restrict__ s, unsigned short* __restrict__ d, int n){
  int i = (blockIdx.x * blockDim.x + threadIdx.x) * 4;
  if (i >= n) return;
  vf4 f = *reinterpret_cast<const vf4*>(s + i);
  vs4 o;
  o[0] = (short)f2bf(f[0]); o[1] = (short)f2bf(f[1]);
  o[2] = (short)f2bf(f[2]); o[3] = (short)f2bf(f[3]);
  *reinterpret_cast<vs4*>(d + i) = o;
}

// ---------------- GEMM: C[M,N] = A[M,K] * B[N,K]^T (+bias), 2-phase dbuf ----------
// LDS tiles are [row][64] bf16 with 16B-slot XOR swizzle: phys_slot = slot ^ (row&7).

DEV void stage_bf16(const unsigned short* __restrict__ g, long row0, int K, int kt,
                    unsigned short* lds, int lane, int wid){
#pragma unroll
  for (int i = 0; i < 4; ++i){
    int stripe = wid*32 + i*8;                 // wave-uniform LDS base row
    int row = stripe + (lane >> 3);
    int chunk = (lane & 7) ^ (row & 7);        // pre-swizzle the global source
    const unsigned short* src = g + (row0 + row) * (long)K + kt + chunk*8;
    gload_lds16(src, &lds[stripe*64]);
  }
}

DEV vs8 lds_frag(const unsigned short* lds, int row, int slot){
  return *reinterpret_cast<const vs8*>(&lds[row*64 + (slot ^ (row & 7))*8]);
}

template<int OUT_F32, int BIAS_ROW>
__global__ __launch_bounds__(256)
void gemm_bt(const unsigned short* __restrict__ Ap, const unsigned short* __restrict__ Bp,
             const float* __restrict__ bias, void* __restrict__ Cp,
             int M, int N, int K, float oscale, long aB, long bB, long cB)
{
  __shared__ unsigned short As[2][128*64];
  __shared__ unsigned short Bs[2][128*64];
  const int tid = threadIdx.x, lane = tid & 63, wid = tid >> 6;
  const int nt = N >> 7, mt = M >> 7;
  int idx = blockIdx.x;
  const int per = mt * nt;
  const int batch = idx / per; idx -= batch * per;
  const long m0 = (long)(idx / nt) * 128;
  const long n0 = (long)(idx % nt) * 128;
  const int wm = (wid >> 1) * 64, wn = (wid & 1) * 64;
  const int cl = lane & 15, gr = lane >> 4;
  const unsigned short* Ab = Ap + aB*batch;
  const unsigned short* Bb = Bp + bB*batch;

  vf4 acc[4][4] = {};

  // prologue: stage tile 0
  stage_bf16(Ab, m0, K, 0, As[0], lane, wid);
  stage_bf16(Bb, n0, K, 0, Bs[0], lane, wid);
  __syncthreads();

  int cur = 0;
  for (int kt = 0; kt < K; kt += 64){
    if (kt + 64 < K){                      // issue next-tile loads BEFORE compute (T3 2-phase)
      stage_bf16(Ab, m0, K, kt + 64, As[cur ^ 1], lane, wid);
      stage_bf16(Bb, n0, K, kt + 64, Bs[cur ^ 1], lane, wid);
    }
    const unsigned short* Asb = As[cur];
    const unsigned short* Bsb = Bs[cur];
#pragma unroll
    for (int ks = 0; ks < 2; ++ks){
      vs8 af[4], bf[4];
#pragma unroll
      for (int mi = 0; mi < 4; ++mi) af[mi] = lds_frag(Asb, wm + mi*16 + cl, ks*4 + gr);
#pragma unroll
      for (int ni = 0; ni < 4; ++ni) bf[ni] = lds_frag(Bsb, wn + ni*16 + cl, ks*4 + gr);
#pragma unroll
      for (int mi = 0; mi < 4; ++mi)
#pragma unroll
        for (int ni = 0; ni < 4; ++ni)
          acc[mi][ni] = __builtin_amdgcn_mfma_f32_16x16x32_bf16(af[mi], bf[ni], acc[mi][ni], 0, 0, 0);
    }
    __syncthreads();                       // drains vmcnt (next tile staged) + lgkm
    cur ^= 1;
  }

  // epilogue: D layout col = lane&15, row = (lane>>4)*4 + r  [guide m89]
#pragma unroll
  for (int mi = 0; mi < 4; ++mi)
#pragma unroll
    for (int ni = 0; ni < 4; ++ni)
#pragma unroll
      for (int r = 0; r < 4; ++r){
        long m = m0 + wm + mi*16 + gr*4 + r;
        long n = n0 + wn + ni*16 + cl;
        float v = (acc[mi][ni][r] + (BIAS_ROW ? bias[m] : bias[n])) * oscale;
        if (OUT_F32) (((float*)Cp) + cB*batch)[m*(long)N + n] = v;
        else (((unsigned short*)Cp) + cB*batch)[m*(long)N + n] = f2bf(v);
      }
}

// ---------------- flash attention (swapped QK^T, KVBLK=64, 8-wave blocks) --------
// q,k: [B,S,1024] bf16 (col = h*64+d), q pre-scaled by (1/8)*log2(e).
// vT:  [B, 1024(h*64+d), S] bf16.
// Block = 8 waves (512 thr); wave owns 16 q-rows; block covers 128 q-rows of one (b,h).
// K/V tile (64 kv) staged in double-buffered LDS shared by all 8 waves
// (halves per-wave staging cost + K/V L2 traffic vs 4-wave blocks).
// Per-wave compute identical to the round-6/7-verified 16x16x32 path.
__global__ __launch_bounds__(512)
void attn_kernel(const unsigned short* __restrict__ qg, const unsigned short* __restrict__ kg,
                 const unsigned short* __restrict__ vg, unsigned short* __restrict__ og)
{
  __shared__ __align__(16) unsigned short Ks[2][64*64];    // [64 kv][8 slot ^ (kv&7)][8]
  __shared__ __align__(16) unsigned short Vs[2][8*64*8];   // [8 kv-slot][64 d][8]
  __shared__ __align__(16) unsigned short Pl[8][16*72];    // per-wave P^T: [16 q][64 kv + 8 pad]
  const int tid = threadIdx.x, lane = tid & 63, wid = tid >> 6;
  const int cl = lane & 15, gr = lane >> 4;
  const int bid = blockIdx.x;
  const int qb = bid & 15, h = (bid >> 4) & 15, b = bid >> 8;
  const int s0 = qb*128 + wid*16;

  // Q B-fragments (verified): col=cl=q, k=d = kc*32 + gr*8 + e
  const unsigned short* qp = qg + ((long)(b*2048 + s0 + cl))*1024 + h*64 + gr*8;
  vs8 q0 = *(const vs8*)(qp);
  vs8 q1 = *(const vs8*)(qp + 32);

  const unsigned short* kb = kg + ((long)b*2048)*1024 + h*64;
  const unsigned short* vb = vg + ((long)(b*1024) + h*64)*2048;

  vf4 o0 = {}, o1 = {}, o2 = {}, o3 = {};
  float m = -__builtin_inff(), lsum = 0.f;

  const int krow = tid >> 3;                          // 0..63 (one row per thread)
  const int kchunk = ((tid & 7) ^ (krow & 7)) * 8;    // pre-swizzled source chunk
  const int vd = tid >> 3, vsl = tid & 7;             // V: d row 0..63, kv-slot 0..7
  const int kbase = (tid & 448) * 8;                  // wave-uniform LDS dest base (wave*512)
  unsigned short* Pw = Pl[wid];

  // prologue: stage tile 0
  gload_lds16(kb + (long)krow*1024 + kchunk, &Ks[0][kbase]);
  {
    vs8 va = *(const vs8*)(vb + (long)vd*2048 + vsl*8);
    *(vs8*)(&Vs[0][(vsl*64 + vd)*8]) = va;
  }
  __syncthreads();

  int cur = 0;
  for (int j0 = 0; j0 < 2048; j0 += 64){
    const int more = (j0 + 64) < 2048;
    vs8 va;
    if (more){
      const long nj = j0 + 64;
      gload_lds16(kb + (nj + krow)*1024 + kchunk, &Ks[cur ^ 1][kbase]);
      va = *(const vs8*)(vb + (long)vd*2048 + nj + vsl*8);
    }
    const unsigned short* ksb = Ks[cur];
    const unsigned short* vsb = Vs[cur];

    // S^T = K * Q^T: 4 kv-subtiles of 16; lane holds S[kv=jt*16+gr*4+r][q=cl]
    vf4 s[4];
#pragma unroll
    for (int jt = 0; jt < 4; ++jt){
      vf4 z = {};
      vs8 aA = lds_frag(ksb, jt*16 + cl, gr);
      z = __builtin_amdgcn_mfma_f32_16x16x32_bf16(aA, q0, z, 0, 0, 0);
      vs8 aB = lds_frag(ksb, jt*16 + cl, 4 + gr);
      z = __builtin_amdgcn_mfma_f32_16x16x32_bf16(aB, q1, z, 0, 0, 0);
      s[jt] = z;
    }

    // tile max (16 own + cross-gr via 2 shfl), log2-domain prescaled
    float t0 = fmaxf(fmaxf(s[0][0], s[0][1]), fmaxf(s[0][2], s[0][3]));
    float t1 = fmaxf(fmaxf(s[1][0], s[1][1]), fmaxf(s[1][2], s[1][3]));
    float t2 = fmaxf(fmaxf(s[2][0], s[2][1]), fmaxf(s[2][2], s[2][3]));
    float t3 = fmaxf(fmaxf(s[3][0], s[3][1]), fmaxf(s[3][2], s[3][3]));
    float t = fmaxf(fmaxf(t0, t1), fmaxf(t2, t3));
    t = fmaxf(t, __shfl_xor(t, 16));
    t = fmaxf(t, __shfl_xor(t, 32));

    if (__any(t > m + 8.f)){            // defer-max (T13); first tile always taken
      float mn = fmaxf(m, t);
      float al = __builtin_amdgcn_exp2f(m - mn);
      m = mn; lsum *= al;
#pragma unroll
      for (int r = 0; r < 4; ++r){ o0[r] *= al; o1[r] *= al; o2[r] *= al; o3[r] *= al; }
    }

#pragma unroll
    for (int jt = 0; jt < 4; ++jt)
#pragma unroll
      for (int r = 0; r < 4; ++r)
        s[jt][r] = __builtin_amdgcn_exp2f(s[jt][r] - m);
    lsum += (((s[0][0]+s[0][1]) + (s[0][2]+s[0][3])) + ((s[1][0]+s[1][1]) + (s[1][2]+s[1][3])))
          + (((s[2][0]+s[2][1]) + (s[2][2]+s[2][3])) + ((s[3][0]+s[3][1]) + (s[3][2]+s[3][3])));

    // P^T -> per-wave LDS (row q=cl, col kv = jt*16+gr*4+r) via v_cvt_pk_bf16_f32
#pragma unroll
    for (int jt = 0; jt < 4; ++jt){
      int2 w;
      w.x = cvtpk(s[jt][0], s[jt][1]);
      w.y = cvtpk(s[jt][2], s[jt][3]);
      *reinterpret_cast<int2*>(&Pw[cl*72 + jt*16 + gr*4]) = w;
    }
    vs8 pa0 = *reinterpret_cast<const vs8*>(&Pw[cl*72 + gr*8]);        // kv 0..31 chunk
    vs8 pa1 = *reinterpret_cast<const vs8*>(&Pw[cl*72 + 32 + gr*8]);   // kv 32..63 chunk

    // O^T += V^T * P^T (A row = d within tile, k = kv)
    o0 = __builtin_amdgcn_mfma_f32_16x16x32_bf16(*(const vs8*)(vsb + (gr*64 +  0 + cl)*8), pa0, o0, 0, 0, 0);
    o1 = __builtin_amdgcn_mfma_f32_16x16x32_bf16(*(const vs8*)(vsb + (gr*64 + 16 + cl)*8), pa0, o1, 0, 0, 0);
    o2 = __builtin_amdgcn_mfma_f32_16x16x32_bf16(*(const vs8*)(vsb + (gr*64 + 32 + cl)*8), pa0, o2, 0, 0, 0);
    o3 = __builtin_amdgcn_mfma_f32_16x16x32_bf16(*(const vs8*)(vsb + (gr*64 + 48 + cl)*8), pa0, o3, 0, 0, 0);
    o0 = __builtin_amdgcn_mfma_f32_16x16x32_bf16(*(const vs8*)(vsb + ((4+gr)*64 +  0 + cl)*8), pa1, o0, 0, 0, 0);
    o1 = __builtin_amdgcn_mfma_f32_16x16x32_bf16(*(const vs8*)(vsb + ((4+gr)*64 + 16 + cl)*8), pa1, o1, 0, 0, 0);
    o2 = __builtin_amdgcn_mfma_f32_16x16x32_bf16(*(const vs8*)(vsb + ((4+gr)*64 + 32 + cl)*8), pa1, o2, 0, 0, 0);
    o3 = __builtin_amdgcn_mfma_f32_16x16x32_bf16(*(const vs8*)(vsb + ((4+gr)*64 + 48 + cl)*8), pa1, o3, 0, 0, 0);

    if (more)                               // write-late V staging (T14)
      *(vs8*)(&Vs[cur ^ 1][(vsl*64 + vd)*8]) = va;
    __syncthreads();
    cur ^= 1;
  }

  // epilogue: combine l over gr halves, write O[q=cl][d = dt*16 + gr*4 + r]
  float ls = lsum;
  ls += __shfl_xor(ls, 16);
  ls += __shfl_xor(ls, 32);
  float inv = 1.0f / ls;
  unsigned short* ob = og + ((long)(b*2048 + s0 + cl))*1024 + h*64 + gr*4;
  vs4 w0, w1, w2, w3;
#pragma unroll
  for (int r = 0; r < 4; ++r){
    w0[r] = (short)f2bf(o0[r] * inv);
    w1[r] = (short)f2bf(o1[r] * inv);
    w2[r] = (short)f2bf(o2[r] * inv);
    w3[r] = (short)f2bf(o3[r] * inv);
  }
  *(vs4*)(ob +  0) = w0;
  *(vs4*)(ob + 16) = w1;
  *(vs4*)(ob + 32) = w2;
  *(vs4*)(ob + 48) = w3;
}

// ---------------- launcher ----------------
extern "C" void kernel_launch(void* const* d_in, const int* in_sizes, int n_in,
                              void* d_out, int out_size, void* d_ws, size_t ws_size,
                              hipStream_t stream)
{
  (void)in_sizes; (void)n_in; (void)out_size; (void)ws_size;
  const float* Q  = (const float*)d_in[0];
  const float* K  = (const float*)d_in[1];
  const float* V  = (const float*)d_in[2];
  const float* bq = (const float*)d_in[4];
  const float* bk = (const float*)d_in[6];
  const float* bv = (const float*)d_in[8];
  const float* bo = (const float*)d_in[10];
  const float* Wq = (const float*)d_in[3];
  const float* Wk = (const float*)d_in[5];
  const float* Wv = (const float*)d_in[7];
  const float* Wo = (const float*)d_in[9];

  unsigned short* q   = (unsigned short*)d_ws;                 // [4,2048,1024] bf16
  unsigned short* k   = q   + (size_t)8*1024*1024;             // [4,2048,1024]
  unsigned short* vT  = k   + (size_t)8*1024*1024;             // [4,1024,2048]
  unsigned short* ctx = vT  + (size_t)8*1024*1024;             // [4,2048,1024]
  unsigned short* wqb = ctx + (size_t)8*1024*1024;             // [1024,1024]
  unsigned short* wkb = wqb + (size_t)1024*1024;
  unsigned short* wvb = wkb + (size_t)1024*1024;
  unsigned short* wob = wvb + (size_t)1024*1024;

  // bf16 input aliases (dead regions, stream-ordered):
  //   Qb -> ctx buffer (ctx not written until attn; q-proj consumes Qb first)
  //   Kb/Vb -> d_out halves (d_out only written by the final projection)
  unsigned short* Qb = ctx;
  unsigned short* Kb = (unsigned short*)d_out;
  unsigned short* Vb = Kb + (size_t)8*1024*1024;

  const int WN = 1024*1024;
  const int AN = 4*2048*1024;
  cvt_w<<<1024, 256, 0, stream>>>(Wq, wqb, WN);
  cvt_w<<<1024, 256, 0, stream>>>(Wk, wkb, WN);
  cvt_w<<<1024, 256, 0, stream>>>(Wv, wvb, WN);
  cvt_w<<<1024, 256, 0, stream>>>(Wo, wob, WN);
  cvt_w<<<8192, 256, 0, stream>>>(Q, Qb, AN);
  cvt_w<<<8192, 256, 0, stream>>>(K, Kb, AN);
  cvt_w<<<8192, 256, 0, stream>>>(V, Vb, AN);

  const float qscale = 0.125f * 1.4426950408889634f;  // 1/sqrt(DK) * log2(e)

  // q = (Q @ Wq^T + bq) * qscale    [8192,1024]
  gemm_bt<0,0><<<512, 256, 0, stream>>>(Qb, wqb, bq, q, 8192, 1024, 1024, qscale, 0, 0, 0);
  // k = K @ Wk^T + bk               [8192,1024]
  gemm_bt<0,0><<<512, 256, 0, stream>>>(Kb, wkb, bk, k, 8192, 1024, 1024, 1.0f, 0, 0, 0);
  // vT[b] = Wv @ V_b^T + bv(row)    [1024,2048] per batch
  gemm_bt<0,1><<<512, 256, 0, stream>>>(wvb, Vb, bv, vT, 1024, 2048, 1024, 1.0f,
                                        0, (long)2048*1024, (long)1024*2048);
  // attention -> ctx [4,2048,1024]  (overwrites Qb after q-proj is done)
  attn_kernel<<<1024, 512, 0, stream>>>(q, k, vT, ctx);
  // out = ctx @ Wo^T + bo  (fp32)   (overwrites Kb/Vb after they're consumed)
  gemm_bt<1,0><<<512, 256, 0, stream>>>(ctx, wob, bo, d_out, 8192, 1024, 1024, 1.0f, 0, 0, 0);
}